// Round 1
// baseline (395.166 us; speedup 1.0000x reference)
//
#include <hip/hip_runtime.h>
#include <hip/hip_bf16.h>
#include <stdint.h>

typedef __attribute__((ext_vector_type(8))) short bf16x8;
typedef __attribute__((ext_vector_type(4))) float f32x4;
typedef __attribute__((ext_vector_type(8))) unsigned short ushort8;
typedef __attribute__((ext_vector_type(4))) unsigned short ushort4v;

#define DEVINL __device__ __forceinline__

static constexpr int BB  = 4;
static constexpr int SS  = 2048;
static constexpr int HID = 1024;
static constexpr int NH  = 16;
static constexpr int DH  = 64;

DEVINL unsigned short f2bf(float f) {
  unsigned u = __builtin_bit_cast(unsigned, f);
  u += 0x7fffu + ((u >> 16) & 1u);   // RNE
  return (unsigned short)(u >> 16);
}

DEVINL void gload_lds16(const void* g, void* lds) {
  __builtin_amdgcn_global_load_lds(
      (__attribute__((address_space(1))) unsigned int*)(g),
      (__attribute__((address_space(3))) unsigned int*)(lds), 16, 0, 0);
}

// ---------------- weight f32 -> bf16 ----------------
__global__ void cvt_f32_to_bf16(const float* __restrict__ src,
                                unsigned short* __restrict__ dst, int n) {
  int i = (blockIdx.x * 256 + threadIdx.x) * 4;
  if (i >= n) return;
  float4 v = *(const float4*)(src + i);
  ushort4v h;
  h.x = f2bf(v.x); h.y = f2bf(v.y); h.z = f2bf(v.z); h.w = f2bf(v.w);
  *(ushort4v*)(dst + i) = h;
}

// ---------------- GEMM: C[m,n] = sum_k A[m,k]*Bw[n,k] + bias[n] ----------------
// 128x128 tile, BK=32, 4 waves (2x2), each wave 64x64 (4x4 frags of 16x16x32).
// LDS tiles [128][32] bf16, XOR-swizzled: byte ^= ((row&3)<<4).
template <int A_BF16, int OUT_F32>
__launch_bounds__(256)
__global__ void gemm_bt(const void* __restrict__ Ap,
                        const unsigned short* __restrict__ Bw,
                        const float* __restrict__ bias,
                        void* __restrict__ Cp, int M, int N, int K) {
  __shared__ __align__(16) unsigned char As[128 * 32 * 2];
  __shared__ __align__(16) unsigned char Bs[128 * 32 * 2];
  const int nb = N >> 7;
  const int bm = blockIdx.x / nb, bn = blockIdx.x % nb;
  const int m0 = bm << 7, n0 = bn << 7;
  const int t = threadIdx.x, lane = t & 63, wv = t >> 6;
  const int wr = wv >> 1, wc = wv & 1;
  const int l15 = lane & 15, l4 = lane >> 4;

  f32x4 acc[4][4] = {};

  for (int k0 = 0; k0 < K; k0 += 32) {
    // stage B (bf16) via global_load_lds, source pre-swizzled
#pragma unroll
    for (int j = 0; j < 2; ++j) {
      int p = (wv * 2 + j) * 1024 + lane * 16;
      int row = p >> 6;
      int colb = (p & 63) ^ ((row & 3) << 4);
      gload_lds16(Bw + (size_t)(n0 + row) * K + k0 + (colb >> 1),
                  Bs + (wv * 2 + j) * 1024);
    }
    if (A_BF16) {
      const unsigned short* Ab = (const unsigned short*)Ap;
#pragma unroll
      for (int j = 0; j < 2; ++j) {
        int p = (wv * 2 + j) * 1024 + lane * 16;
        int row = p >> 6;
        int colb = (p & 63) ^ ((row & 3) << 4);
        gload_lds16(Ab + (size_t)(m0 + row) * K + k0 + (colb >> 1),
                    As + (wv * 2 + j) * 1024);
      }
    } else {
      // A is fp32: reg-stage + convert to bf16 into swizzled LDS
      const float* Af = (const float*)Ap;
#pragma unroll
      for (int i = 0; i < 4; ++i) {
        int fidx = t + i * 256;          // float4 index within 128x32 tile
        int row = fidx >> 3;             // 8 float4 per 32-float row
        int colf = (fidx & 7) << 2;
        float4 v = *(const float4*)(Af + (size_t)(m0 + row) * K + k0 + colf);
        ushort4v h;
        h.x = f2bf(v.x); h.y = f2bf(v.y); h.z = f2bf(v.z); h.w = f2bf(v.w);
        int byte = (fidx * 8) ^ ((row & 3) << 4);
        *(ushort4v*)(As + byte) = h;
      }
    }
    __syncthreads();

    bf16x8 af[4], bfr[4];
#pragma unroll
    for (int m = 0; m < 4; ++m) {
      int r = wr * 64 + m * 16 + l15;
      int byte = (r * 64 + l4 * 16) ^ ((r & 3) << 4);
      af[m] = *(const bf16x8*)(As + byte);
    }
#pragma unroll
    for (int n = 0; n < 4; ++n) {
      int r = wc * 64 + n * 16 + l15;
      int byte = (r * 64 + l4 * 16) ^ ((r & 3) << 4);
      bfr[n] = *(const bf16x8*)(Bs + byte);
    }
#pragma unroll
    for (int m = 0; m < 4; ++m)
#pragma unroll
      for (int n = 0; n < 4; ++n)
        acc[m][n] = __builtin_amdgcn_mfma_f32_16x16x32_bf16(af[m], bfr[n],
                                                            acc[m][n], 0, 0, 0);
    __syncthreads();
  }

  // epilogue: C/D layout col=lane&15, row=(lane>>4)*4+r
#pragma unroll
  for (int n = 0; n < 4; ++n) {
    int col = n0 + wc * 64 + n * 16 + l15;
    float bc = bias[col];
#pragma unroll
    for (int m = 0; m < 4; ++m) {
      int rowb = m0 + wr * 64 + m * 16 + l4 * 4;
#pragma unroll
      for (int r = 0; r < 4; ++r) {
        float val = acc[m][n][r] + bc;
        if (OUT_F32)
          ((float*)Cp)[(size_t)(rowb + r) * N + col] = val;
        else
          ((unsigned short*)Cp)[(size_t)(rowb + r) * N + col] = f2bf(val);
      }
    }
  }
}

// ---------------- V transpose: Vh[B,S,H,D] -> Vt[B,H,D,S] ----------------
__launch_bounds__(256)
__global__ void transpose_v(const unsigned short* __restrict__ Vh,
                            unsigned short* __restrict__ Vt) {
  __shared__ unsigned short Ts[64][65];
  const int bid = blockIdx.x;
  const int st = bid & 31, h = (bid >> 5) & 15, b = bid >> 9;
  const int s0 = st << 6;
  const int t = threadIdx.x;
  {
    int si = t >> 2, jq = (t & 3) * 16;
    const unsigned short* src =
        Vh + ((size_t)(b * SS + s0 + si)) * HID + h * DH + jq;
    ushort8 v0 = *(const ushort8*)src;
    ushort8 v1 = *(const ushort8*)(src + 8);
#pragma unroll
    for (int e = 0; e < 8; ++e) {
      Ts[si][jq + e] = v0[e];
      Ts[si][jq + 8 + e] = v1[e];
    }
  }
  __syncthreads();
  {
    int d = t >> 2, sq = (t & 3) * 16;
    ushort8 o0, o1;
#pragma unroll
    for (int e = 0; e < 8; ++e) {
      o0[e] = Ts[sq + e][d];
      o1[e] = Ts[sq + 8 + e][d];
    }
    unsigned short* dst =
        Vt + ((size_t)((b * NH + h) * DH + d)) * SS + s0 + sq;
    *(ushort8*)dst = o0;
    *(ushort8*)(dst + 8) = o1;
  }
}

// ---------------- flash attention ----------------
// grid: B*H*(S/64). block 256 = 4 waves; wave w owns q-rows [64*qt + 16w, +16).
// K tile and V^T tile 64x64 bf16 in LDS, swizzled byte ^= ((row&7)<<4).
__launch_bounds__(256)
__global__ void attn_kernel(const unsigned short* __restrict__ Qh,
                            const unsigned short* __restrict__ Kh,
                            const unsigned short* __restrict__ Vt,
                            const int* __restrict__ pad,
                            const int* __restrict__ pcausal,
                            unsigned short* __restrict__ Out) {
  __shared__ __align__(16) unsigned char Ks[8192];
  __shared__ __align__(16) unsigned char Vts[8192];
  __shared__ __align__(16) unsigned char Ps[8192];
  const int bid = blockIdx.x;
  const int qt = bid & 31, h = (bid >> 5) & 15, b = bid >> 9;
  const int q0 = qt << 6;
  const int t = threadIdx.x, lane = t & 63, wv = t >> 6;
  const int l15 = lane & 15, l4 = lane >> 4;
  const int causal = *pcausal;

  // Q fragments straight from global (A-frag: row=l&15, k=(l>>4)*8..)
  const unsigned short* Qbase =
      Qh + ((size_t)(b * SS) + q0 + wv * 16 + l15) * HID + h * DH;
  bf16x8 qf[2];
  qf[0] = *(const bf16x8*)(Qbase + l4 * 8);
  qf[1] = *(const bf16x8*)(Qbase + 32 + l4 * 8);

  const int rowloc = wv * 16 + l4 * 4;  // + r  (C/D row layout)
  int qidx[4];
  bool padded[4];
#pragma unroll
  for (int r = 0; r < 4; ++r) {
    qidx[r] = q0 + rowloc + r;
    padded[r] = (pad[b * SS + qidx[r]] == 0);
  }

  f32x4 oacc[4] = {};
  float mrow[4] = {-__builtin_inff(), -__builtin_inff(), -__builtin_inff(),
                   -__builtin_inff()};
  float lrow[4] = {0.f, 0.f, 0.f, 0.f};

  const int nkt = causal ? (qt + 1) : (SS >> 6);
  for (int kt = 0; kt < nkt; ++kt) {
    const int k0 = kt << 6;
#pragma unroll
    for (int j = 0; j < 2; ++j) {
      int p = (wv * 2 + j) * 1024 + lane * 16;
      int r = p >> 7;
      int cb = (p & 127) ^ ((r & 7) << 4);
      gload_lds16(Kh + ((size_t)(b * SS) + k0 + r) * HID + h * DH + (cb >> 1),
                  Ks + (wv * 2 + j) * 1024);
      gload_lds16(Vt + ((size_t)((b * NH + h) * DH + r)) * SS + k0 + (cb >> 1),
                  Vts + (wv * 2 + j) * 1024);
    }
    __syncthreads();

    // S = Q K^T  (16x64 strip per wave)
    f32x4 sacc[4] = {};
#pragma unroll
    for (int c = 0; c < 4; ++c) {
      int rk = c * 16 + l15;
#pragma unroll
      for (int s = 0; s < 2; ++s) {
        int byte = (rk * 128 + s * 64 + l4 * 16) ^ ((rk & 7) << 4);
        bf16x8 kf = *(const bf16x8*)(Ks + byte);
        sacc[c] = __builtin_amdgcn_mfma_f32_16x16x32_bf16(qf[s], kf, sacc[c],
                                                          0, 0, 0);
      }
    }

    // scale + masks
    float sv[4][4];  // [c][r]
#pragma unroll
    for (int c = 0; c < 4; ++c) {
#pragma unroll
      for (int r = 0; r < 4; ++r) {
        float x = sacc[c][r] * 0.125f;
        if (padded[r]) x = -1e9f;
        sv[c][r] = x;
      }
    }
    if (causal && kt == qt) {
#pragma unroll
      for (int c = 0; c < 4; ++c) {
        int kidx = k0 + c * 16 + l15;
#pragma unroll
        for (int r = 0; r < 4; ++r)
          if (kidx > qidx[r]) sv[c][r] = -__builtin_inff();
      }
    }

    // online softmax (row spread over 16 lanes: shfl_xor 1/2/4/8)
#pragma unroll
    for (int r = 0; r < 4; ++r) {
      float tm = fmaxf(fmaxf(sv[0][r], sv[1][r]), fmaxf(sv[2][r], sv[3][r]));
#pragma unroll
      for (int off = 1; off < 16; off <<= 1)
        tm = fmaxf(tm, __shfl_xor(tm, off));
      float mnew = fmaxf(mrow[r], tm);
      float corr = __expf(mrow[r] - mnew);
      mrow[r] = mnew;
      float rsum = 0.f;
#pragma unroll
      for (int c = 0; c < 4; ++c) {
        float p = __expf(sv[c][r] - mnew);
        sv[c][r] = p;
        rsum += p;
      }
#pragma unroll
      for (int off = 1; off < 16; off <<= 1) rsum += __shfl_xor(rsum, off);
      lrow[r] = lrow[r] * corr + rsum;
#pragma unroll
      for (int f = 0; f < 4; ++f) oacc[f][r] *= corr;
    }

    // P -> per-wave LDS (swizzled), read back as A-frags
    unsigned char* Pw = Ps + wv * 2048;
#pragma unroll
    for (int r = 0; r < 4; ++r) {
      int prow = l4 * 4 + r;
      int sw = (prow & 7) << 4;
#pragma unroll
      for (int c = 0; c < 4; ++c) {
        int byte = (prow * 128 + (c * 16 + l15) * 2) ^ sw;
        *(unsigned short*)(Pw + byte) = f2bf(sv[c][r]);
      }
    }
    bf16x8 pa[2];
#pragma unroll
    for (int ks = 0; ks < 2; ++ks) {
      int byte = (l15 * 128 + ks * 64 + l4 * 16) ^ ((l15 & 7) << 4);
      pa[ks] = *(const bf16x8*)(Pw + byte);
    }

    // O += P * V   (B-frag = rows of V^T)
#pragma unroll
    for (int f = 0; f < 4; ++f) {
      int rd = f * 16 + l15;
#pragma unroll
      for (int ks = 0; ks < 2; ++ks) {
        int byte = (rd * 128 + ks * 64 + l4 * 16) ^ ((rd & 7) << 4);
        bf16x8 vf = *(const bf16x8*)(Vts + byte);
        oacc[f] = __builtin_amdgcn_mfma_f32_16x16x32_bf16(pa[ks], vf, oacc[f],
                                                          0, 0, 0);
      }
    }
    __syncthreads();
  }

  // normalize + store hidden (bf16, [B,S,HID] natural layout)
#pragma unroll
  for (int r = 0; r < 4; ++r) {
    float inv = 1.0f / lrow[r];
    size_t rowoff = ((size_t)(b * SS) + q0 + rowloc + r) * HID + h * DH;
#pragma unroll
    for (int f = 0; f < 4; ++f)
      Out[rowoff + f * 16 + l15] = f2bf(oacc[f][r] * inv);
  }
}

// ---------------- launch ----------------
extern "C" void kernel_launch(void* const* d_in, const int* in_sizes, int n_in,
                              void* d_out, int out_size, void* d_ws,
                              size_t ws_size, hipStream_t stream) {
  const float* q = (const float*)d_in[0];
  const float* k = (const float*)d_in[1];
  const float* v = (const float*)d_in[2];
  const int* pad = (const int*)d_in[3];
  const float* Wq = (const float*)d_in[4];
  const float* bq = (const float*)d_in[5];
  const float* Wk = (const float*)d_in[6];
  const float* bk = (const float*)d_in[7];
  const float* Wv = (const float*)d_in[8];
  const float* bv = (const float*)d_in[9];
  const float* Wo = (const float*)d_in[10];
  const float* bo = (const float*)d_in[11];
  const int* iscausal = (const int*)d_in[12];
  float* out = (float*)d_out;

  // workspace: 4 bf16 weights (8 MB) + Qh + Kh + Vt + tmp (4x16.8 MB) = 75.5 MB
  unsigned short* Wqb = (unsigned short*)d_ws;
  unsigned short* Wkb = Wqb + 1024 * 1024;
  unsigned short* Wvb = Wkb + 1024 * 1024;
  unsigned short* Wob = Wvb + 1024 * 1024;
  unsigned short* Qh = Wob + 1024 * 1024;
  unsigned short* Kh = Qh + (size_t)8192 * 1024;
  unsigned short* Vtp = Kh + (size_t)8192 * 1024;
  unsigned short* Htmp = Vtp + (size_t)8192 * 1024;  // Vh, then hidden

  cvt_f32_to_bf16<<<1024, 256, 0, stream>>>(Wq, Wqb, 1024 * 1024);
  cvt_f32_to_bf16<<<1024, 256, 0, stream>>>(Wk, Wkb, 1024 * 1024);
  cvt_f32_to_bf16<<<1024, 256, 0, stream>>>(Wv, Wvb, 1024 * 1024);
  cvt_f32_to_bf16<<<1024, 256, 0, stream>>>(Wo, Wob, 1024 * 1024);

  gemm_bt<0, 0><<<512, 256, 0, stream>>>(q, Wqb, bq, Qh, 8192, 1024, 1024);
  gemm_bt<0, 0><<<512, 256, 0, stream>>>(k, Wkb, bk, Kh, 8192, 1024, 1024);
  gemm_bt<0, 0><<<512, 256, 0, stream>>>(v, Wvb, bv, Htmp, 8192, 1024, 1024);

  transpose_v<<<2048, 256, 0, stream>>>(Htmp, Vtp);

  attn_kernel<<<2048, 256, 0, stream>>>(Qh, Kh, Vtp, pad, iscausal, Htmp);

  gemm_bt<1, 1><<<512, 256, 0, stream>>>(Htmp, Wob, bo, out, 8192, 1024, 1024);
}

// Round 2
// 282.946 us; speedup vs baseline: 1.3966x; 1.3966x over previous
//
#include <hip/hip_runtime.h>
#include <hip/hip_bf16.h>
#include <stdint.h>

typedef __attribute__((ext_vector_type(8))) short bf16x8;
typedef __attribute__((ext_vector_type(4))) float f32x4;
typedef __attribute__((ext_vector_type(16))) float f32x16;
typedef __attribute__((ext_vector_type(8))) unsigned short ushort8;
typedef __attribute__((ext_vector_type(4))) unsigned short ushort4v;
typedef __attribute__((ext_vector_type(4))) unsigned int u32x4;

#define DEVINL __device__ __forceinline__

static constexpr int BB  = 4;
static constexpr int SS  = 2048;
static constexpr int HID = 1024;
static constexpr int NH  = 16;
static constexpr int DH  = 64;

DEVINL unsigned short f2bf(float f) {
  unsigned u = __builtin_bit_cast(unsigned, f);
  u += 0x7fffu + ((u >> 16) & 1u);   // RNE
  return (unsigned short)(u >> 16);
}

DEVINL unsigned cvt_pk_bf16(float lo, float hi) {
  unsigned r;
  asm("v_cvt_pk_bf16_f32 %0, %1, %2" : "=v"(r) : "v"(lo), "v"(hi));
  return r;
}

DEVINL void gload_lds16(const void* g, void* lds) {
  __builtin_amdgcn_global_load_lds(
      (__attribute__((address_space(1))) unsigned int*)(g),
      (__attribute__((address_space(3))) unsigned int*)(lds), 16, 0, 0);
}

// ---------------- weight f32 -> bf16 ----------------
__global__ void cvt_f32_to_bf16(const float* __restrict__ src,
                                unsigned short* __restrict__ dst, int n) {
  int i = (blockIdx.x * 256 + threadIdx.x) * 4;
  if (i >= n) return;
  float4 v = *(const float4*)(src + i);
  ushort4v h;
  h.x = f2bf(v.x); h.y = f2bf(v.y); h.z = f2bf(v.z); h.w = f2bf(v.w);
  *(ushort4v*)(dst + i) = h;
}

// ---------------- GEMM: C[m,n] = sum_k A[m,k]*Bw[n,k] + bias[n] ----------------
// (unchanged from R1 — verified correct)
template <int A_BF16, int OUT_F32>
__launch_bounds__(256)
__global__ void gemm_bt(const void* __restrict__ Ap,
                        const unsigned short* __restrict__ Bw,
                        const float* __restrict__ bias,
                        void* __restrict__ Cp, int M, int N, int K) {
  __shared__ __align__(16) unsigned char As[128 * 32 * 2];
  __shared__ __align__(16) unsigned char Bs[128 * 32 * 2];
  const int nb = N >> 7;
  const int bm = blockIdx.x / nb, bn = blockIdx.x % nb;
  const int m0 = bm << 7, n0 = bn << 7;
  const int t = threadIdx.x, lane = t & 63, wv = t >> 6;
  const int wr = wv >> 1, wc = wv & 1;
  const int l15 = lane & 15, l4 = lane >> 4;

  f32x4 acc[4][4] = {};

  for (int k0 = 0; k0 < K; k0 += 32) {
#pragma unroll
    for (int j = 0; j < 2; ++j) {
      int p = (wv * 2 + j) * 1024 + lane * 16;
      int row = p >> 6;
      int colb = (p & 63) ^ ((row & 3) << 4);
      gload_lds16(Bw + (size_t)(n0 + row) * K + k0 + (colb >> 1),
                  Bs + (wv * 2 + j) * 1024);
    }
    if (A_BF16) {
      const unsigned short* Ab = (const unsigned short*)Ap;
#pragma unroll
      for (int j = 0; j < 2; ++j) {
        int p = (wv * 2 + j) * 1024 + lane * 16;
        int row = p >> 6;
        int colb = (p & 63) ^ ((row & 3) << 4);
        gload_lds16(Ab + (size_t)(m0 + row) * K + k0 + (colb >> 1),
                    As + (wv * 2 + j) * 1024);
      }
    } else {
      const float* Af = (const float*)Ap;
#pragma unroll
      for (int i = 0; i < 4; ++i) {
        int fidx = t + i * 256;
        int row = fidx >> 3;
        int colf = (fidx & 7) << 2;
        float4 v = *(const float4*)(Af + (size_t)(m0 + row) * K + k0 + colf);
        ushort4v h;
        h.x = f2bf(v.x); h.y = f2bf(v.y); h.z = f2bf(v.z); h.w = f2bf(v.w);
        int byte = (fidx * 8) ^ ((row & 3) << 4);
        *(ushort4v*)(As + byte) = h;
      }
    }
    __syncthreads();

    bf16x8 af[4], bfr[4];
#pragma unroll
    for (int m = 0; m < 4; ++m) {
      int r = wr * 64 + m * 16 + l15;
      int byte = (r * 64 + l4 * 16) ^ ((r & 3) << 4);
      af[m] = *(const bf16x8*)(As + byte);
    }
#pragma unroll
    for (int n = 0; n < 4; ++n) {
      int r = wc * 64 + n * 16 + l15;
      int byte = (r * 64 + l4 * 16) ^ ((r & 3) << 4);
      bfr[n] = *(const bf16x8*)(Bs + byte);
    }
#pragma unroll
    for (int m = 0; m < 4; ++m)
#pragma unroll
      for (int n = 0; n < 4; ++n)
        acc[m][n] = __builtin_amdgcn_mfma_f32_16x16x32_bf16(af[m], bfr[n],
                                                            acc[m][n], 0, 0, 0);
    __syncthreads();
  }

#pragma unroll
  for (int n = 0; n < 4; ++n) {
    int col = n0 + wc * 64 + n * 16 + l15;
    float bc = bias[col];
#pragma unroll
    for (int m = 0; m < 4; ++m) {
      int rowb = m0 + wr * 64 + m * 16 + l4 * 4;
#pragma unroll
      for (int r = 0; r < 4; ++r) {
        float val = acc[m][n][r] + bc;
        if (OUT_F32)
          ((float*)Cp)[(size_t)(rowb + r) * N + col] = val;
        else
          ((unsigned short*)Cp)[(size_t)(rowb + r) * N + col] = f2bf(val);
      }
    }
  }
}

// ---------------- V transpose: Vh[B,S,H,D] -> Vt[B,H,D,S] ----------------
__launch_bounds__(256)
__global__ void transpose_v(const unsigned short* __restrict__ Vh,
                            unsigned short* __restrict__ Vt) {
  __shared__ unsigned short Ts[64][65];
  const int bid = blockIdx.x;
  const int st = bid & 31, h = (bid >> 5) & 15, b = bid >> 9;
  const int s0 = st << 6;
  const int t = threadIdx.x;
  {
    int si = t >> 2, jq = (t & 3) * 16;
    const unsigned short* src =
        Vh + ((size_t)(b * SS + s0 + si)) * HID + h * DH + jq;
    ushort8 v0 = *(const ushort8*)src;
    ushort8 v1 = *(const ushort8*)(src + 8);
#pragma unroll
    for (int e = 0; e < 8; ++e) {
      Ts[si][jq + e] = v0[e];
      Ts[si][jq + 8 + e] = v1[e];
    }
  }
  __syncthreads();
  {
    int d = t >> 2, sq = (t & 3) * 16;
    ushort8 o0, o1;
#pragma unroll
    for (int e = 0; e < 8; ++e) {
      o0[e] = Ts[sq + e][d];
      o1[e] = Ts[sq + 8 + e][d];
    }
    unsigned short* dst =
        Vt + ((size_t)((b * NH + h) * DH + d)) * SS + s0 + sq;
    *(ushort8*)dst = o0;
    *(ushort8*)(dst + 8) = o1;
  }
}

// ---------------- flash attention, swapped-QK^T 32x32 ----------------
// grid: B*H*8 pairs. block 256 = 4 waves; wave wv owns q-rows
// [128*qt + 32*wv, +32). Each block handles q-tiles {p, 15-p} -> uniform
// 36 k-tiles/block under causal. Lane owns one q (col=lane&31); its 64
// k-values per tile live in regs (32) + partner lane^32 (32).
__launch_bounds__(256)
__global__ void attn_kernel(const unsigned short* __restrict__ Qh,
                            const unsigned short* __restrict__ Kh,
                            const unsigned short* __restrict__ Vt,
                            const int* __restrict__ pad,
                            const int* __restrict__ pcausal,
                            unsigned short* __restrict__ Out) {
  __shared__ __align__(16) unsigned char Ks[8192];
  __shared__ __align__(16) unsigned char Vs[8192];
  const int bid = blockIdx.x;
  const int pr = bid & 7, h = (bid >> 3) & 15, b = bid >> 7;
  const int t = threadIdx.x, lane = t & 63, wv = t >> 6;
  const int l31 = lane & 31, hi = lane >> 5;
  const int causal = *pcausal;
  const float SCL = 0.18033688011112042f;  // (1/8) * log2(e)

  for (int half = 0; half < 2; ++half) {
    const int qt = half ? (15 - pr) : pr;
    const int q0 = qt << 7;
    const int qrow = q0 + wv * 32 + l31;  // this lane's q index
    const bool padded = (pad[b * SS + qrow] == 0);

    // Q as B-fragments (col=q, k-dim=d): lane reads 8 d at dd*16+hi*8
    const unsigned short* Qb = Qh + ((size_t)(b * SS) + qrow) * HID + h * DH;
    bf16x8 qf[4];
#pragma unroll
    for (int dd = 0; dd < 4; ++dd)
      qf[dd] = *(const bf16x8*)(Qb + dd * 16 + hi * 8);

    f32x16 oacc[2] = {};  // O^T[d][q]: d-blocks 0..1, lane col=q
    float m = -__builtin_inff(), l = 0.f;

    const int nkt = causal ? (2 * qt + 2) : (SS >> 6);
    for (int kt = 0; kt < nkt; ++kt) {
      const int k0 = kt << 6;
#pragma unroll
      for (int j = 0; j < 2; ++j) {
        int pb = (wv * 2 + j) * 1024 + lane * 16;
        int r_ = pb >> 7;
        int cb = (pb & 127) ^ ((r_ & 7) << 4);
        gload_lds16(Kh + ((size_t)(b * SS) + k0 + r_) * HID + h * DH + (cb >> 1),
                    Ks + (wv * 2 + j) * 1024);
        gload_lds16(Vt + ((size_t)((b * NH + h) * DH + r_)) * SS + k0 + (cb >> 1),
                    Vs + (wv * 2 + j) * 1024);
      }
      __syncthreads();

      const bool active = (!causal) || (k0 <= q0 + wv * 32 + 31);
      if (active) {
        // S^T = K * Q : out row = k (kb*32 + crow), col = q
        f32x16 sacc[2] = {};
#pragma unroll
        for (int kb = 0; kb < 2; ++kb) {
#pragma unroll
          for (int dd = 0; dd < 4; ++dd) {
            int krow = kb * 32 + l31;
            int byte = (krow * 128 + dd * 32 + hi * 16) ^ ((l31 & 7) << 4);
            bf16x8 kf = *(const bf16x8*)(Ks + byte);
            sacc[kb] = __builtin_amdgcn_mfma_f32_32x32x16_bf16(kf, qf[dd],
                                                               sacc[kb], 0, 0, 0);
          }
        }
        // scale (log2 domain) + masks
        const bool needmask = causal && (k0 + 63 > q0 + wv * 32);
#pragma unroll
        for (int kb = 0; kb < 2; ++kb) {
#pragma unroll
          for (int r = 0; r < 16; ++r) {
            float x = sacc[kb][r] * SCL;
            if (padded) x = -1e9f;
            if (needmask) {
              int kidx = k0 + kb * 32 + (r & 3) + 8 * (r >> 2) + 4 * hi;
              if (kidx > qrow) x = -__builtin_inff();
            }
            sacc[kb][r] = x;
          }
        }
        // online softmax: row max = in-lane 31 + partner exchange
        float tmax = sacc[0][0];
#pragma unroll
        for (int r = 1; r < 16; ++r) tmax = fmaxf(tmax, sacc[0][r]);
#pragma unroll
        for (int r = 0; r < 16; ++r) tmax = fmaxf(tmax, sacc[1][r]);
        tmax = fmaxf(tmax, __shfl_xor(tmax, 32));
        float mnew = fmaxf(m, tmax);
        float corr = exp2f(m - mnew);
        m = mnew;
        float ls = 0.f;
#pragma unroll
        for (int kb = 0; kb < 2; ++kb)
#pragma unroll
          for (int r = 0; r < 16; ++r) {
            float p = exp2f(sacc[kb][r] - mnew);
            sacc[kb][r] = p;
            ls += p;
          }
        l = l * corr + ls;
#pragma unroll
        for (int db = 0; db < 2; ++db)
#pragma unroll
          for (int r = 0; r < 16; ++r) oacc[db][r] *= corr;

        // pack P^T into PV B-fragments (k local layout: kk*16+hi*8+e)
        // lane holds k = kb*32 + (r&3)+8*(r>>2)+4*hi; words w[i]=(p2i,p2i+1)
        bf16x8 pf[4];
#pragma unroll
        for (int kb = 0; kb < 2; ++kb) {
          unsigned w0 = cvt_pk_bf16(sacc[kb][0], sacc[kb][1]);
          unsigned w1 = cvt_pk_bf16(sacc[kb][2], sacc[kb][3]);
          unsigned w2 = cvt_pk_bf16(sacc[kb][4], sacc[kb][5]);
          unsigned w3 = cvt_pk_bf16(sacc[kb][6], sacc[kb][7]);
          unsigned w4 = cvt_pk_bf16(sacc[kb][8], sacc[kb][9]);
          unsigned w5 = cvt_pk_bf16(sacc[kb][10], sacc[kb][11]);
          unsigned w6 = cvt_pk_bf16(sacc[kb][12], sacc[kb][13]);
          unsigned w7 = cvt_pk_bf16(sacc[kb][14], sacc[kb][15]);
          // exchange with partner lane (lane^32)
          unsigned t0 = __shfl_xor(hi ? w0 : w2, 32);
          unsigned t1 = __shfl_xor(hi ? w1 : w3, 32);
          unsigned t2 = __shfl_xor(hi ? w4 : w6, 32);
          unsigned t3 = __shfl_xor(hi ? w5 : w7, 32);
          u32x4 lo, hf;
          lo[0] = hi ? t0 : w0;
          lo[1] = hi ? t1 : w1;
          lo[2] = hi ? w2 : t0;
          lo[3] = hi ? w3 : t1;
          hf[0] = hi ? t2 : w4;
          hf[1] = hi ? t3 : w5;
          hf[2] = hi ? w6 : t2;
          hf[3] = hi ? w7 : t3;
          pf[2 * kb] = __builtin_bit_cast(bf16x8, lo);
          pf[2 * kb + 1] = __builtin_bit_cast(bf16x8, hf);
        }
        // O^T += V^T * P^T
#pragma unroll
        for (int db = 0; db < 2; ++db) {
#pragma unroll
          for (int kk = 0; kk < 4; ++kk) {
            int drow = db * 32 + l31;
            int byte = (drow * 128 + kk * 32 + hi * 16) ^ ((l31 & 7) << 4);
            bf16x8 vf = *(const bf16x8*)(Vs + byte);
            oacc[db] = __builtin_amdgcn_mfma_f32_32x32x16_bf16(vf, pf[kk],
                                                               oacc[db], 0, 0, 0);
          }
        }
      }
      __syncthreads();
    }

    float ltot = l + __shfl_xor(l, 32);
    float inv = 1.0f / ltot;
    size_t rowoff = ((size_t)(b * SS) + qrow) * HID + h * DH;
#pragma unroll
    for (int db = 0; db < 2; ++db) {
#pragma unroll
      for (int g = 0; g < 4; ++g) {
        ushort4v o;
#pragma unroll
        for (int j = 0; j < 4; ++j) o[j] = f2bf(oacc[db][4 * g + j] * inv);
        *(ushort4v*)(Out + rowoff + db * 32 + 8 * g + 4 * hi) = o;
      }
    }
  }
}

// ---------------- launch ----------------
extern "C" void kernel_launch(void* const* d_in, const int* in_sizes, int n_in,
                              void* d_out, int out_size, void* d_ws,
                              size_t ws_size, hipStream_t stream) {
  const float* q = (const float*)d_in[0];
  const float* k = (const float*)d_in[1];
  const float* v = (const float*)d_in[2];
  const int* pad = (const int*)d_in[3];
  const float* Wq = (const float*)d_in[4];
  const float* bq = (const float*)d_in[5];
  const float* Wk = (const float*)d_in[6];
  const float* bk = (const float*)d_in[7];
  const float* Wv = (const float*)d_in[8];
  const float* bv = (const float*)d_in[9];
  const float* Wo = (const float*)d_in[10];
  const float* bo = (const float*)d_in[11];
  const int* iscausal = (const int*)d_in[12];
  float* out = (float*)d_out;

  unsigned short* Wqb = (unsigned short*)d_ws;
  unsigned short* Wkb = Wqb + 1024 * 1024;
  unsigned short* Wvb = Wkb + 1024 * 1024;
  unsigned short* Wob = Wvb + 1024 * 1024;
  unsigned short* Qh = Wob + 1024 * 1024;
  unsigned short* Kh = Qh + (size_t)8192 * 1024;
  unsigned short* Vtp = Kh + (size_t)8192 * 1024;
  unsigned short* Htmp = Vtp + (size_t)8192 * 1024;

  cvt_f32_to_bf16<<<1024, 256, 0, stream>>>(Wq, Wqb, 1024 * 1024);
  cvt_f32_to_bf16<<<1024, 256, 0, stream>>>(Wk, Wkb, 1024 * 1024);
  cvt_f32_to_bf16<<<1024, 256, 0, stream>>>(Wv, Wvb, 1024 * 1024);
  cvt_f32_to_bf16<<<1024, 256, 0, stream>>>(Wo, Wob, 1024 * 1024);

  gemm_bt<0, 0><<<512, 256, 0, stream>>>(q, Wqb, bq, Qh, 8192, 1024, 1024);
  gemm_bt<0, 0><<<512, 256, 0, stream>>>(k, Wkb, bk, Kh, 8192, 1024, 1024);
  gemm_bt<0, 0><<<512, 256, 0, stream>>>(v, Wvb, bv, Htmp, 8192, 1024, 1024);

  transpose_v<<<2048, 256, 0, stream>>>(Htmp, Vtp);

  attn_kernel<<<512, 256, 0, stream>>>(Qh, Kh, Vtp, pad, iscausal, Htmp);

  gemm_bt<1, 1><<<512, 256, 0, stream>>>(Htmp, Wob, bo, out, 8192, 1024, 1024);
}

// Round 3
// 261.930 us; speedup vs baseline: 1.5087x; 1.0802x over previous
//
#include <hip/hip_runtime.h>
#include <hip/hip_bf16.h>
#include <stdint.h>

typedef __attribute__((ext_vector_type(8))) short bf16x8;
typedef __attribute__((ext_vector_type(4))) float f32x4;
typedef __attribute__((ext_vector_type(16))) float f32x16;
typedef __attribute__((ext_vector_type(8))) unsigned short ushort8;
typedef __attribute__((ext_vector_type(4))) unsigned short ushort4v;
typedef __attribute__((ext_vector_type(4))) unsigned int u32x4;

#define DEVINL __device__ __forceinline__

static constexpr int BB  = 4;
static constexpr int SS  = 2048;
static constexpr int HID = 1024;
static constexpr int NH  = 16;
static constexpr int DH  = 64;

DEVINL unsigned short f2bf(float f) {
  unsigned u = __builtin_bit_cast(unsigned, f);
  u += 0x7fffu + ((u >> 16) & 1u);   // RNE
  return (unsigned short)(u >> 16);
}

DEVINL unsigned cvt_pk_bf16(float lo, float hi) {
  unsigned r;
  asm("v_cvt_pk_bf16_f32 %0, %1, %2" : "=v"(r) : "v"(lo), "v"(hi));
  return r;
}

DEVINL void gload_lds16(const void* g, void* lds) {
  __builtin_amdgcn_global_load_lds(
      (__attribute__((address_space(1))) unsigned int*)(g),
      (__attribute__((address_space(3))) unsigned int*)(lds), 16, 0, 0);
}

// ---------------- f32 -> bf16 (4 elems/thread) ----------------
__global__ void cvt_f32_to_bf16(const float* __restrict__ src,
                                unsigned short* __restrict__ dst, int n) {
  int i = (blockIdx.x * 256 + threadIdx.x) * 4;
  if (i >= n) return;
  float4 v = *(const float4*)(src + i);
  ushort4v h;
  h.x = f2bf(v.x); h.y = f2bf(v.y); h.z = f2bf(v.z); h.w = f2bf(v.w);
  *(ushort4v*)(dst + i) = h;
}

// all 4 weight matrices in one launch; dst = [4][1M]
__global__ void cvt4_weights(const float* __restrict__ a,
                             const float* __restrict__ b,
                             const float* __restrict__ c,
                             const float* __restrict__ d,
                             unsigned short* __restrict__ dst) {
  int which = blockIdx.x >> 10;
  const float* src = which == 0 ? a : which == 1 ? b : which == 2 ? c : d;
  int i = ((blockIdx.x & 1023) * 256 + threadIdx.x) * 4;
  float4 v = *(const float4*)(src + i);
  ushort4v h;
  h.x = f2bf(v.x); h.y = f2bf(v.y); h.z = f2bf(v.z); h.w = f2bf(v.w);
  *(ushort4v*)(dst + which * 1048576 + i) = h;
}

// ---------------- GEMM: C[m,n] = (sum_k A[m,k]*Bw[n,k] + bias[n])*oscale ----
// 128x128 tile, BK=32, 4 waves (2x2), each wave 64x64 (4x4 frags of 16x16x32).
// A and B both bf16, staged via global_load_lds, swizzle byte^=((row&3)<<4).
template <int OUT_F32>
__launch_bounds__(256)
__global__ void gemm_bt(const unsigned short* __restrict__ Ab,
                        const unsigned short* __restrict__ Bw,
                        const float* __restrict__ bias,
                        void* __restrict__ Cp, int M, int N, int K,
                        float oscale) {
  __shared__ __align__(16) unsigned char As[128 * 32 * 2];
  __shared__ __align__(16) unsigned char Bs[128 * 32 * 2];
  const int nb = N >> 7;
  const int bm = blockIdx.x / nb, bn = blockIdx.x % nb;
  const int m0 = bm << 7, n0 = bn << 7;
  const int t = threadIdx.x, lane = t & 63, wv = t >> 6;
  const int wr = wv >> 1, wc = wv & 1;
  const int l15 = lane & 15, l4 = lane >> 4;

  f32x4 acc[4][4] = {};

  for (int k0 = 0; k0 < K; k0 += 32) {
#pragma unroll
    for (int j = 0; j < 2; ++j) {
      int p = (wv * 2 + j) * 1024 + lane * 16;
      int row = p >> 6;
      int colb = (p & 63) ^ ((row & 3) << 4);
      gload_lds16(Bw + (size_t)(n0 + row) * K + k0 + (colb >> 1),
                  Bs + (wv * 2 + j) * 1024);
      gload_lds16(Ab + (size_t)(m0 + row) * K + k0 + (colb >> 1),
                  As + (wv * 2 + j) * 1024);
    }
    __syncthreads();

    bf16x8 af[4], bfr[4];
#pragma unroll
    for (int m = 0; m < 4; ++m) {
      int r = wr * 64 + m * 16 + l15;
      int byte = (r * 64 + l4 * 16) ^ ((r & 3) << 4);
      af[m] = *(const bf16x8*)(As + byte);
    }
#pragma unroll
    for (int n = 0; n < 4; ++n) {
      int r = wc * 64 + n * 16 + l15;
      int byte = (r * 64 + l4 * 16) ^ ((r & 3) << 4);
      bfr[n] = *(const bf16x8*)(Bs + byte);
    }
#pragma unroll
    for (int m = 0; m < 4; ++m)
#pragma unroll
      for (int n = 0; n < 4; ++n)
        acc[m][n] = __builtin_amdgcn_mfma_f32_16x16x32_bf16(af[m], bfr[n],
                                                            acc[m][n], 0, 0, 0);
    __syncthreads();
  }

#pragma unroll
  for (int n = 0; n < 4; ++n) {
    int col = n0 + wc * 64 + n * 16 + l15;
    float bc = bias[col];
#pragma unroll
    for (int m = 0; m < 4; ++m) {
      int rowb = m0 + wr * 64 + m * 16 + l4 * 4;
#pragma unroll
      for (int r = 0; r < 4; ++r) {
        float val = (acc[m][n][r] + bc) * oscale;
        if (OUT_F32)
          ((float*)Cp)[(size_t)(rowb + r) * N + col] = val;
        else
          ((unsigned short*)Cp)[(size_t)(rowb + r) * N + col] = f2bf(val);
      }
    }
  }
}

// ---------------- V transpose: Vh[B,S,H,D] -> Vt[B,H,D,S] ----------------
__launch_bounds__(256)
__global__ void transpose_v(const unsigned short* __restrict__ Vh,
                            unsigned short* __restrict__ Vt) {
  __shared__ unsigned short Ts[64][65];
  const int bid = blockIdx.x;
  const int st = bid & 31, h = (bid >> 5) & 15, b = bid >> 9;
  const int s0 = st << 6;
  const int t = threadIdx.x;
  {
    int si = t >> 2, jq = (t & 3) * 16;
    const unsigned short* src =
        Vh + ((size_t)(b * SS + s0 + si)) * HID + h * DH + jq;
    ushort8 v0 = *(const ushort8*)src;
    ushort8 v1 = *(const ushort8*)(src + 8);
#pragma unroll
    for (int e = 0; e < 8; ++e) {
      Ts[si][jq + e] = v0[e];
      Ts[si][jq + 8 + e] = v1[e];
    }
  }
  __syncthreads();
  {
    int d = t >> 2, sq = (t & 3) * 16;
    ushort8 o0, o1;
#pragma unroll
    for (int e = 0; e < 8; ++e) {
      o0[e] = Ts[sq + e][d];
      o1[e] = Ts[sq + 8 + e][d];
    }
    unsigned short* dst =
        Vt + ((size_t)((b * NH + h) * DH + d)) * SS + s0 + sq;
    *(ushort8*)dst = o0;
    *(ushort8*)(dst + 8) = o1;
  }
}

// ---------------- flash attention, swapped-QK^T 32x32 ----------------
// Q pre-scaled by (1/8)*log2e in its projection; padding pre-folded by
// zeroing Q rows (scores=0 -> uniform softmax over visible keys == ref).
// Defer-max: skip oacc rescale unless wave-any max growth > 8 (log2 dom).
__launch_bounds__(256)
__global__ void attn_kernel(const unsigned short* __restrict__ Qh,
                            const unsigned short* __restrict__ Kh,
                            const unsigned short* __restrict__ Vt,
                            const int* __restrict__ pad,
                            const int* __restrict__ pcausal,
                            unsigned short* __restrict__ Out) {
  __shared__ __align__(16) unsigned char Ks[8192];
  __shared__ __align__(16) unsigned char Vs[8192];
  // XCD swizzle: all 8 q-pair blocks of one (b,h) share an XCD (512 blocks)
  const int bid = (blockIdx.x & 7) * 64 + (blockIdx.x >> 3);
  const int pr = bid & 7, h = (bid >> 3) & 15, b = bid >> 7;
  const int t = threadIdx.x, lane = t & 63, wv = t >> 6;
  const int l31 = lane & 31, hi = lane >> 5;
  const int causal = *pcausal;

  for (int half = 0; half < 2; ++half) {
    const int qt = half ? (15 - pr) : pr;
    const int q0 = qt << 7;
    const int qrow = q0 + wv * 32 + l31;  // this lane's q index
    const bool padded = (pad[b * SS + qrow] == 0);

    // Q as B-fragments (col=q, k-dim=d): lane reads 8 d at dd*16+hi*8
    const unsigned short* Qb = Qh + ((size_t)(b * SS) + qrow) * HID + h * DH;
    bf16x8 qf[4];
#pragma unroll
    for (int dd = 0; dd < 4; ++dd) {
      qf[dd] = *(const bf16x8*)(Qb + dd * 16 + hi * 8);
      if (padded) qf[dd] = (bf16x8)0;
    }

    f32x16 oacc[2] = {};  // O^T[d][q]: d-blocks 0..1, lane col=q
    float m = -__builtin_inff(), l = 0.f;

    const int nkt = causal ? (2 * qt + 2) : (SS >> 6);
    for (int kt = 0; kt < nkt; ++kt) {
      const int k0 = kt << 6;
#pragma unroll
      for (int j = 0; j < 2; ++j) {
        int pb = (wv * 2 + j) * 1024 + lane * 16;
        int r_ = pb >> 7;
        int cb = (pb & 127) ^ ((r_ & 7) << 4);
        gload_lds16(Kh + ((size_t)(b * SS) + k0 + r_) * HID + h * DH + (cb >> 1),
                    Ks + (wv * 2 + j) * 1024);
        gload_lds16(Vt + ((size_t)((b * NH + h) * DH + r_)) * SS + k0 + (cb >> 1),
                    Vs + (wv * 2 + j) * 1024);
      }
      __syncthreads();

      const bool active = (!causal) || (k0 <= q0 + wv * 32 + 31);
      if (active) {
        // S^T = K * Q : out row = k (kb*32 + crow), col = q
        f32x16 sacc[2] = {};
#pragma unroll
        for (int kb = 0; kb < 2; ++kb) {
#pragma unroll
          for (int dd = 0; dd < 4; ++dd) {
            int krow = kb * 32 + l31;
            int byte = (krow * 128 + dd * 32 + hi * 16) ^ ((l31 & 7) << 4);
            bf16x8 kf = *(const bf16x8*)(Ks + byte);
            sacc[kb] = __builtin_amdgcn_mfma_f32_32x32x16_bf16(kf, qf[dd],
                                                               sacc[kb], 0, 0, 0);
          }
        }
        // causal mask (diagonal tiles only)
        if (causal && (k0 + 63 > q0 + wv * 32)) {
#pragma unroll
          for (int kb = 0; kb < 2; ++kb)
#pragma unroll
            for (int r = 0; r < 16; ++r) {
              int kidx = k0 + kb * 32 + (r & 3) + 8 * (r >> 2) + 4 * hi;
              if (kidx > qrow) sacc[kb][r] = -__builtin_inff();
            }
        }
        // row max (max3-fused tree) + partner exchange
        float ta = fmaxf(sacc[0][0], sacc[0][1]);
        float tb = fmaxf(sacc[0][2], sacc[0][3]);
#pragma unroll
        for (int r = 4; r < 16; r += 4) {
          ta = fmaxf(ta, fmaxf(sacc[0][r], sacc[0][r + 1]));
          tb = fmaxf(tb, fmaxf(sacc[0][r + 2], sacc[0][r + 3]));
        }
#pragma unroll
        for (int r = 0; r < 16; r += 4) {
          ta = fmaxf(ta, fmaxf(sacc[1][r], sacc[1][r + 1]));
          tb = fmaxf(tb, fmaxf(sacc[1][r + 2], sacc[1][r + 3]));
        }
        float tmax = fmaxf(ta, tb);
        tmax = fmaxf(tmax, __shfl_xor(tmax, 32));
        // defer-max: rescale only when wave-any growth > 8
        if (__any(tmax > m + 8.0f)) {
          float mnew = fmaxf(m, tmax);
          float corr = exp2f(m - mnew);
          m = mnew;
          l *= corr;
#pragma unroll
          for (int db = 0; db < 2; ++db)
#pragma unroll
            for (int r = 0; r < 16; ++r) oacc[db][r] *= corr;
        }
        float ls = 0.f;
#pragma unroll
        for (int kb = 0; kb < 2; ++kb)
#pragma unroll
          for (int r = 0; r < 16; ++r) {
            float p = exp2f(sacc[kb][r] - m);
            sacc[kb][r] = p;
            ls += p;
          }
        l += ls;

        // pack P^T into PV B-fragments (k local layout: kk*16+hi*8+e)
        bf16x8 pf[4];
#pragma unroll
        for (int kb = 0; kb < 2; ++kb) {
          unsigned w0 = cvt_pk_bf16(sacc[kb][0], sacc[kb][1]);
          unsigned w1 = cvt_pk_bf16(sacc[kb][2], sacc[kb][3]);
          unsigned w2 = cvt_pk_bf16(sacc[kb][4], sacc[kb][5]);
          unsigned w3 = cvt_pk_bf16(sacc[kb][6], sacc[kb][7]);
          unsigned w4 = cvt_pk_bf16(sacc[kb][8], sacc[kb][9]);
          unsigned w5 = cvt_pk_bf16(sacc[kb][10], sacc[kb][11]);
          unsigned w6 = cvt_pk_bf16(sacc[kb][12], sacc[kb][13]);
          unsigned w7 = cvt_pk_bf16(sacc[kb][14], sacc[kb][15]);
          unsigned t0 = __shfl_xor(hi ? w0 : w2, 32);
          unsigned t1 = __shfl_xor(hi ? w1 : w3, 32);
          unsigned t2 = __shfl_xor(hi ? w4 : w6, 32);
          unsigned t3 = __shfl_xor(hi ? w5 : w7, 32);
          u32x4 lo, hf;
          lo[0] = hi ? t0 : w0;
          lo[1] = hi ? t1 : w1;
          lo[2] = hi ? w2 : t0;
          lo[3] = hi ? w3 : t1;
          hf[0] = hi ? t2 : w4;
          hf[1] = hi ? t3 : w5;
          hf[2] = hi ? w6 : t2;
          hf[3] = hi ? w7 : t3;
          pf[2 * kb] = __builtin_bit_cast(bf16x8, lo);
          pf[2 * kb + 1] = __builtin_bit_cast(bf16x8, hf);
        }
        // O^T += V^T * P^T
#pragma unroll
        for (int db = 0; db < 2; ++db) {
#pragma unroll
          for (int kk = 0; kk < 4; ++kk) {
            int drow = db * 32 + l31;
            int byte = (drow * 128 + kk * 32 + hi * 16) ^ ((l31 & 7) << 4);
            bf16x8 vf = *(const bf16x8*)(Vs + byte);
            oacc[db] = __builtin_amdgcn_mfma_f32_32x32x16_bf16(vf, pf[kk],
                                                               oacc[db], 0, 0, 0);
          }
        }
      }
      __syncthreads();
    }

    float ltot = l + __shfl_xor(l, 32);
    float inv = 1.0f / ltot;
    size_t rowoff = ((size_t)(b * SS) + qrow) * HID + h * DH;
#pragma unroll
    for (int db = 0; db < 2; ++db) {
#pragma unroll
      for (int g = 0; g < 4; ++g) {
        ushort4v o;
#pragma unroll
        for (int j = 0; j < 4; ++j) o[j] = f2bf(oacc[db][4 * g + j] * inv);
        *(ushort4v*)(Out + rowoff + db * 32 + 8 * g + 4 * hi) = o;
      }
    }
  }
}

// ---------------- launch ----------------
extern "C" void kernel_launch(void* const* d_in, const int* in_sizes, int n_in,
                              void* d_out, int out_size, void* d_ws,
                              size_t ws_size, hipStream_t stream) {
  const float* q = (const float*)d_in[0];
  const float* k = (const float*)d_in[1];
  const float* v = (const float*)d_in[2];
  const int* pad = (const int*)d_in[3];
  const float* Wq = (const float*)d_in[4];
  const float* bq = (const float*)d_in[5];
  const float* Wk = (const float*)d_in[6];
  const float* bk = (const float*)d_in[7];
  const float* Wv = (const float*)d_in[8];
  const float* bv = (const float*)d_in[9];
  const float* Wo = (const float*)d_in[10];
  const float* bo = (const float*)d_in[11];
  const int* iscausal = (const int*)d_in[12];
  float* out = (float*)d_out;

  const float SCL = 0.18033688011112042f;  // (1/8) * log2(e)
  const int NQKV = BB * SS * HID;          // 8388608

  // workspace (ushort units): weights 4x1M, Ab 8M, Qh/Kh/Vt/Htmp 8M each = 88MB
  unsigned short* Wqb = (unsigned short*)d_ws;
  unsigned short* Wkb = Wqb + 1048576;
  unsigned short* Wvb = Wkb + 1048576;
  unsigned short* Wob = Wvb + 1048576;
  unsigned short* Ab = Wob + 1048576;
  unsigned short* Qh = Ab + (size_t)NQKV;
  unsigned short* Kh = Qh + (size_t)NQKV;
  unsigned short* Vtp = Kh + (size_t)NQKV;
  unsigned short* Htmp = Vtp + (size_t)NQKV;

  cvt4_weights<<<4096, 256, 0, stream>>>(Wq, Wk, Wv, Wo, Wqb);

  cvt_f32_to_bf16<<<8192, 256, 0, stream>>>(q, Ab, NQKV);
  gemm_bt<0><<<512, 256, 0, stream>>>(Ab, Wqb, bq, Qh, 8192, 1024, 1024, SCL);
  cvt_f32_to_bf16<<<8192, 256, 0, stream>>>(k, Ab, NQKV);
  gemm_bt<0><<<512, 256, 0, stream>>>(Ab, Wkb, bk, Kh, 8192, 1024, 1024, 1.0f);
  cvt_f32_to_bf16<<<8192, 256, 0, stream>>>(v, Ab, NQKV);
  gemm_bt<0><<<512, 256, 0, stream>>>(Ab, Wvb, bv, Htmp, 8192, 1024, 1024, 1.0f);

  transpose_v<<<2048, 256, 0, stream>>>(Htmp, Vtp);

  attn_kernel<<<512, 256, 0, stream>>>(Qh, Kh, Vtp, pad, iscausal, Htmp);

  gemm_bt<1><<<512, 256, 0, stream>>>(Htmp, Wob, bo, out, 8192, 1024, 1024, 1.0f);
}